// Round 1
// baseline (641.119 us; speedup 1.0000x reference)
//
#include <hip/hip_runtime.h>

#define NXd 4096
#define NYd 4096
#define Bd  2

// Match reference: compute in double, cast to f32 (jnp.float32(C_MU))
constexpr double DTd   = 1e-11;
constexpr double DXd   = 0.01;
constexpr double EPS0d = 8.854e-12;
constexpr double MU0d  = 4.0 * 3.1415926 * 1e-07;
constexpr float  C_EPS = (float)(DTd / EPS0d / DXd);
constexpr float  C_MU  = (float)(DTd / MU0d / DXd);

__global__ __launch_bounds__(256) void fdtd_step_kernel(
    const float* __restrict__ Ez, const float* __restrict__ Hx,
    const float* __restrict__ Hy,
    float* __restrict__ EzO, float* __restrict__ HxO, float* __restrict__ HyO)
{
    const int j0 = (blockIdx.x * 256 + threadIdx.x) * 4;  // column start
    const int i  = blockIdx.y;                            // row
    const int b  = blockIdx.z;                            // batch
    const size_t base = ((size_t)b * NXd + (size_t)i) * NYd + j0;
    const float* ez = Ez + base;

    const bool has_down = (i < NXd - 1);  // Hx updates rows 0..NX-2
    const bool has_up   = (i > 0);        // Ez updates rows 1..NX-1
    const bool jm_ok    = (j0 > 0);
    const bool jp_ok    = (j0 + 4 < NYd);

    // ---- loads (all float4 16B-aligned; 4 scalar halo loads hit cached lines)
    float4 ec = *(const float4*)(ez);                 // Ez[i][j0..j0+3]
    float ezc0 = jm_ok ? ez[-1] : 0.f;                // Ez[i][j0-1]
    float ezc5 = jp_ok ? ez[4]  : 0.f;                // Ez[i][j0+4]

    float4 ed = make_float4(0.f, 0.f, 0.f, 0.f);      // Ez[i+1][j0..j0+3]
    float ezd0 = 0.f;                                 // Ez[i+1][j0-1]
    if (has_down) {
        ed = *(const float4*)(ez + NYd);
        ezd0 = jm_ok ? ez[NYd - 1] : 0.f;
    }

    float4 eu  = make_float4(0.f, 0.f, 0.f, 0.f);     // Ez[i-1][j0..j0+3]
    float ezu4 = 0.f;                                 // Ez[i-1][j0+4]
    float4 hyu = make_float4(0.f, 0.f, 0.f, 0.f);     // Hy[i-1][j0..j0+3]
    if (has_up) {
        eu   = *(const float4*)(ez - NYd);
        ezu4 = jp_ok ? ez[-NYd + 4] : 0.f;
        hyu  = *(const float4*)(Hy + base - NYd);
    }

    float4 hxc  = *(const float4*)(Hx + base);
    float  hxm1 = jm_ok ? Hx[base - 1] : 0.f;         // Hx[i][j0-1]
    float4 hyc  = *(const float4*)(Hy + base);

    // ---- register arrays (all indices compile-time constant after unroll)
    float ezc[6] = {ezc0, ec.x, ec.y, ec.z, ec.w, ezc5};  // cols j0-1..j0+4
    float ezd[5] = {ezd0, ed.x, ed.y, ed.z, ed.w};        // cols j0-1..j0+3
    float ezu[5] = {eu.x, eu.y, eu.z, eu.w, ezu4};        // cols j0..j0+4
    float hx_[5] = {hxm1, hxc.x, hxc.y, hxc.z, hxc.w};    // cols j0-1..j0+3
    float hy_[4] = {hyc.x, hyc.y, hyc.z, hyc.w};
    float hyu_[4]= {hyu.x, hyu.y, hyu.z, hyu.w};

    // Hx_new[i][j0-1 .. j0+3]  (update applies for all j, only when i < NX-1)
    float hxn[5];
#pragma unroll
    for (int t = 0; t < 5; ++t)
        hxn[t] = has_down ? fmaf(-C_MU, ezd[t] - ezc[t], hx_[t]) : hx_[t];

    // Hy_new[i][j0..j0+3] and Hy_new[i-1][j0..j0+3] (update only when j < NY-1)
    float hyn[4], hyun[4];
#pragma unroll
    for (int k = 0; k < 4; ++k) {
        const bool jn = (j0 + k) < (NYd - 1);
        hyn[k]  = jn ? fmaf(C_MU, ezc[k + 2] - ezc[k + 1], hy_[k])  : hy_[k];
        hyun[k] = jn ? fmaf(C_MU, ezu[k + 1] - ezu[k],     hyu_[k]) : hyu_[k];
    }

    // Ez_new[i][j0..j0+3] (update only for i>=1 && j>=1), uses NEW H values
    float ezn[4];
#pragma unroll
    for (int k = 0; k < 4; ++k) {
        const bool upd = has_up && ((j0 + k) >= 1);
        const float curl = (hyn[k] - hyun[k]) - (hxn[k + 1] - hxn[k]);
        ezn[k] = upd ? fmaf(C_EPS, curl, ezc[k + 1]) : ezc[k + 1];
    }

    *(float4*)(EzO + base) = make_float4(ezn[0], ezn[1], ezn[2], ezn[3]);
    *(float4*)(HxO + base) = make_float4(hxn[1], hxn[2], hxn[3], hxn[4]);
    *(float4*)(HyO + base) = make_float4(hyn[0], hyn[1], hyn[2], hyn[3]);
}

extern "C" void kernel_launch(void* const* d_in, const int* in_sizes, int n_in,
                              void* d_out, int out_size, void* d_ws, size_t ws_size,
                              hipStream_t stream) {
    const float* Ez = (const float*)d_in[0];
    const float* Hx = (const float*)d_in[1];
    const float* Hy = (const float*)d_in[2];
    float* out = (float*)d_out;
    const size_t N = (size_t)Bd * NXd * NYd;

    dim3 grid(NYd / (256 * 4), NXd, Bd);   // 4 x 4096 x 2 blocks
    fdtd_step_kernel<<<grid, dim3(256, 1, 1), 0, stream>>>(
        Ez, Hx, Hy, out, out + N, out + 2 * N);
}